// Round 4
// baseline (56.006 us; speedup 1.0000x reference)
//
#include <hip/hip_runtime.h>

#define NUM_CODE 2048
#define DIM_CODE 512

// One WAVE (64 lanes) per row; 4 independent waves per 256-thread block.
// No LDS, no __syncthreads -- waves are never phase-locked. All 16 float4
// global loads (8x x, 8x noise = 256 B/lane) are issued up front and pinned
// there with sched_barrier(0) so the compiler cannot sink the noise loads
// behind the softmax chain (R1/R2 showed it otherwise keeps VGPR=20 and
// serializes two full HBM round-trips per wave).
__global__ __launch_bounds__(256) void vq_row_kernel(
    const float* __restrict__ x,
    const float* __restrict__ noise,
    const float* __restrict__ codebook,
    float* __restrict__ out)
{
    const int tid  = threadIdx.x;
    const int lane = tid & 63;
    const int wave = tid >> 6;
    const int row  = blockIdx.x * 4 + wave;

    const float4* x4 = (const float4*)(x     + (size_t)row * NUM_CODE);
    const float4* n4 = (const float4*)(noise + (size_t)row * NUM_CODE);

    // lane l, chunk j -> float4 index j*64+l -> elements 256j + 4l .. +3
    float4 a[8];   // x, overwritten with e = exp(x - m)
    float4 nz[8];  // noise
    #pragma unroll
    for (int j = 0; j < 8; ++j) a[j]  = x4[j * 64 + lane];
    #pragma unroll
    for (int j = 0; j < 8; ++j) nz[j] = n4[j * 64 + lane];
    __builtin_amdgcn_sched_barrier(0);  // nothing may cross: loads stay issued here

    // ---- row max (per-thread tree, then 6-step butterfly) ----
    float m = fmaxf(fmaxf(a[0].x, a[0].y), fmaxf(a[0].z, a[0].w));
    #pragma unroll
    for (int j = 1; j < 8; ++j)
        m = fmaxf(m, fmaxf(fmaxf(a[j].x, a[j].y), fmaxf(a[j].z, a[j].w)));
    #pragma unroll
    for (int off = 32; off; off >>= 1)
        m = fmaxf(m, __shfl_xor(m, off));

    // ---- exp + row sum (e overwrites x in place) ----
    float s = 0.f;
    #pragma unroll
    for (int j = 0; j < 8; ++j) {
        a[j].x = expf(a[j].x - m);
        a[j].y = expf(a[j].y - m);
        a[j].z = expf(a[j].z - m);
        a[j].w = expf(a[j].w - m);
        s += (a[j].x + a[j].y) + (a[j].z + a[j].w);
    }
    #pragma unroll
    for (int off = 32; off; off >>= 1)
        s += __shfl_xor(s, off);
    const float inv = 1.0f / s;  // single division (R2 win, kept)

    // ---- argmax(sm - noise), first-index tie-break ----
    // per-thread scan in increasing global index order (256j + 4l + c)
    float bv = -INFINITY; int bi = 0;
    #pragma unroll
    for (int j = 0; j < 8; ++j) {
        const int base = 256 * j + 4 * lane;
        { float v = a[j].x * inv - nz[j].x; if (v > bv) { bv = v; bi = base;     } }
        { float v = a[j].y * inv - nz[j].y; if (v > bv) { bv = v; bi = base + 1; } }
        { float v = a[j].z * inv - nz[j].z; if (v > bv) { bv = v; bi = base + 2; } }
        { float v = a[j].w * inv - nz[j].w; if (v > bv) { bv = v; bi = base + 3; } }
    }
    #pragma unroll
    for (int off = 32; off; off >>= 1) {
        float ov = __shfl_xor(bv, off);
        int   oi = __shfl_xor(bi, off);
        if (ov > bv || (ov == bv && oi < bi)) { bv = ov; bi = oi; }
    }

    // ---- gather codebook[bi] -> out[row]: 64 lanes x 2 float4 = 2 KB ----
    const float4* cb = (const float4*)(codebook + (size_t)bi * DIM_CODE);
    float4*       o  = (float4*)(out + (size_t)row * DIM_CODE);
    o[lane]      = cb[lane];
    o[64 + lane] = cb[64 + lane];
}

extern "C" void kernel_launch(void* const* d_in, const int* in_sizes, int n_in,
                              void* d_out, int out_size, void* d_ws, size_t ws_size,
                              hipStream_t stream) {
    const float* x        = (const float*)d_in[0];
    const float* noise    = (const float*)d_in[1];
    const float* codebook = (const float*)d_in[2];
    float* out            = (float*)d_out;

    const int n_rows = in_sizes[0] / NUM_CODE;  // 16384
    vq_row_kernel<<<n_rows / 4, 256, 0, stream>>>(x, noise, codebook, out);
}